// Round 15
// baseline (123.961 us; speedup 1.0000x reference)
//
#include <hip/hip_runtime.h>
#include <hip/hip_bf16.h>
#include <math.h>

#define D_MODEL 512
#define NTOK 2048
#define QGRP 4
#define NHEAD 8
#define HDIM 64
#define ROWS_PER_T (QGRP * NTOK)          /* 8192 */
#define LN_EPS 1e-5f
#define NCHUNK 16                          /* pair_reduce chunks per pair */

typedef __attribute__((ext_vector_type(8))) short short8;
typedef __attribute__((ext_vector_type(8))) __bf16 bf16x8;
typedef __attribute__((ext_vector_type(4))) float f32x4;

__device__ inline void split2(float y, ushort& h, ushort& l) {
    __hip_bfloat16 hb = __float2bfloat16(y);
    float hf = __bfloat162float(hb);
    __hip_bfloat16 lb = __float2bfloat16(y - hf);
    h = *reinterpret_cast<ushort*>(&hb);
    l = *reinterpret_cast<ushort*>(&lb);
}

__device__ inline float b2f(ushort u) {
    unsigned int x = ((unsigned int)u) << 16;
    return __uint_as_float(x);
}

__device__ inline void split8v(const float4& p0, const float4& p1, bf16x8& bh, bf16x8& bl) {
    float xv[8] = {p0.x, p0.y, p0.z, p0.w, p1.x, p1.y, p1.z, p1.w};
    ushort hs[8], ls[8];
#pragma unroll
    for (int j = 0; j < 8; ++j) split2(xv[j], hs[j], ls[j]);
    bh = *(const bf16x8*)hs;
    bl = *(const bf16x8*)ls;
}

/* ------- Kernel 1: prep — LN+split of q/k/v (blocks 0..6143) AND
   hi/lo split of both weight matrices (blocks 6144..6399) in ONE launch ------- */
__global__ __launch_bounds__(256)
void prep_kernel(const float* __restrict__ q, const float* __restrict__ k,
                 const float* __restrict__ v, const float* __restrict__ gamma,
                 const float* __restrict__ beta,
                 const float* __restrict__ W0, const float* __restrict__ W1,
                 ushort* __restrict__ A3h, ushort* __restrict__ A3l,
                 ushort* __restrict__ Wh0, ushort* __restrict__ Wl0,
                 ushort* __restrict__ Wh1, ushort* __restrict__ Wl1) {
    if (blockIdx.x >= 6144) {                 /* weight split */
        int b = blockIdx.x - 6144;
        int half = b >> 7;
        const float* W = half ? W1 : W0;
        ushort* Wh = half ? Wh1 : Wh0;
        ushort* Wl = half ? Wl1 : Wl0;
        size_t i = ((size_t)(b & 127) * 256 + threadIdx.x) * 8;
        float4 a = *(const float4*)(W + i);
        float4 bb = *(const float4*)(W + i + 4);
        float xv[8] = {a.x, a.y, a.z, a.w, bb.x, bb.y, bb.z, bb.w};
        ushort hs[8], ls[8];
#pragma unroll
        for (int j = 0; j < 8; ++j) split2(xv[j], hs[j], ls[j]);
        *(short8*)(Wh + i) = *(const short8*)hs;
        *(short8*)(Wl + i) = *(const short8*)ls;
        return;
    }
    int wave = threadIdx.x >> 6, lane = threadIdx.x & 63;
    size_t row = (size_t)blockIdx.x * 4 + wave;      /* 0 .. 24575 */
    int t = (int)(row >> 13);
    size_t r = row & 8191;
    const float* src = (t == 0 ? q : (t == 1 ? k : v)) + r * D_MODEL + lane * 8;
    float4 a = *(const float4*)src;
    float4 b = *(const float4*)(src + 4);
    float s  = a.x + a.y + a.z + a.w + b.x + b.y + b.z + b.w;
    float sq = a.x*a.x + a.y*a.y + a.z*a.z + a.w*a.w
             + b.x*b.x + b.y*b.y + b.z*b.z + b.w*b.w;
    for (int m = 1; m < 64; m <<= 1) {
        s  += __shfl_xor(s, m);
        sq += __shfl_xor(sq, m);
    }
    float mu   = s * (1.0f / (float)D_MODEL);
    float var  = sq * (1.0f / (float)D_MODEL) - mu * mu;
    float rstd = 1.0f / sqrtf(var + LN_EPS);
    float4 g0 = *(const float4*)(gamma + lane * 8);
    float4 g1 = *(const float4*)(gamma + lane * 8 + 4);
    float4 t0 = *(const float4*)(beta + lane * 8);
    float4 t1 = *(const float4*)(beta + lane * 8 + 4);
    float xv[8] = {a.x, a.y, a.z, a.w, b.x, b.y, b.z, b.w};
    float gv[8] = {g0.x, g0.y, g0.z, g0.w, g1.x, g1.y, g1.z, g1.w};
    float bv[8] = {t0.x, t0.y, t0.z, t0.w, t1.x, t1.y, t1.z, t1.w};
    ushort hs[8], ls[8];
#pragma unroll
    for (int j = 0; j < 8; ++j) {
        float y = (xv[j] - mu) * rstd * gv[j] + bv[j];
        split2(y, hs[j], ls[j]);
    }
    *(short8*)(A3h + row * D_MODEL + lane * 8) = *(const short8*)hs;
    *(short8*)(A3l + row * D_MODEL + lane * 8) = *(const short8*)ls;
}

/* ------- Kernel 2: split-bf16 MFMA GEMM, 128x128 tile, 4 waves.
   Conflict-free XOR swizzle (r6/r9): BK=32: (r>>1)&3; BK=64: r&7.
   XCD-aware 1-D grid (r14-proven).
   MODE 3 (input proj): BK=32, DOUBLE-buffered LDS software pipeline —
     one barrier/step; ds_write of tile t+1 placed AFTER tile t's MFMAs
     (hides the formerly-serial LDS-write window under compute).
   MODE 2 (out proj): BK=64, single-buffer 2-barrier loop (r11-proven). ------- */
template <int MODE, int BK>
__global__ __launch_bounds__(256)
void gemm_split_kernel(const ushort* __restrict__ Ah, const ushort* __restrict__ Al,
                       const ushort* __restrict__ Wh, const ushort* __restrict__ Wl,
                       const float* __restrict__ bias, float* __restrict__ C,
                       ushort* __restrict__ Ch, ushort* __restrict__ Cl) {
    constexpr int NSTEP = 512 / BK;
    constexpr int NG    = BK / 8;        /* granules per row            */
    constexpr int RPP   = 256 / NG;      /* rows staged per pass        */
    constexpr int NP    = 128 / RPP;     /* passes per matrix half      */
    constexpr int NBUF  = (MODE == 3) ? 2 : 1;

    __shared__ __align__(16) ushort sA[NBUF][2][128][BK];
    __shared__ __align__(16) ushort sW[NBUF][2][128][BK];

    int tid  = threadIdx.x;
    int lane = tid & 63, wid = tid >> 6;
    int wr = wid >> 1, wc = wid & 1;
    int z, xblk, cb;
    if (MODE == 3) {
        int lin = (blockIdx.x & 7) * 96 + (blockIdx.x >> 3);
        xblk = lin / 12;
        int rem = lin % 12;
        z  = rem >> 2;
        cb = rem & 3;
    } else {
        int lin = (blockIdx.x & 7) * 32 + (blockIdx.x >> 3);
        xblk = lin >> 2;
        cb   = lin & 3;
        z    = 0;
    }
    size_t rowBase = (size_t)xblk * 128;
    size_t colBase = (size_t)cb * 128;
    size_t zoff = (size_t)z * ROWS_PER_T * D_MODEL;
    const ushort* gA[2] = {Ah + zoff, Al + zoff};
    const ushort* gW[2] = {Wh, Wl};

    int sr  = tid / NG;                  /* staging row (+p*RPP per pass) */
    int sc8 = tid % NG;                  /* staging 8-elem granule        */

#define SWZ(r) ((BK == 64) ? ((r) & 7) : (((r) >> 1) & 3))

    short8 st[4 * NP];

#define LOADK(KT)                                                                  \
    {                                                                              \
        int idx = 0;                                                               \
        _Pragma("unroll")                                                          \
        for (int hl = 0; hl < 2; ++hl)                                             \
            _Pragma("unroll")                                                      \
            for (int p = 0; p < NP; ++p) {                                         \
                int r = p * RPP + sr;                                              \
                st[idx++] = *(const short8*)(gA[hl] + (rowBase + r) * D_MODEL +    \
                                             (KT) + sc8 * 8);                      \
            }                                                                      \
        _Pragma("unroll")                                                          \
        for (int hl = 0; hl < 2; ++hl)                                             \
            _Pragma("unroll")                                                      \
            for (int p = 0; p < NP; ++p) {                                         \
                int r = p * RPP + sr;                                              \
                st[idx++] = *(const short8*)(gW[hl] + (colBase + r) * D_MODEL +    \
                                             (KT) + sc8 * 8);                      \
            }                                                                      \
    }

#define WRITELDS(BUF)                                                              \
    {                                                                              \
        int idx = 0;                                                               \
        _Pragma("unroll")                                                          \
        for (int hl = 0; hl < 2; ++hl)                                             \
            _Pragma("unroll")                                                      \
            for (int p = 0; p < NP; ++p) {                                         \
                int r = p * RPP + sr;                                              \
                *(short8*)&sA[BUF][hl][r][(sc8 ^ SWZ(r)) << 3] = st[idx++];        \
            }                                                                      \
        _Pragma("unroll")                                                          \
        for (int hl = 0; hl < 2; ++hl)                                             \
            _Pragma("unroll")                                                      \
            for (int p = 0; p < NP; ++p) {                                         \
                int r = p * RPP + sr;                                              \
                *(short8*)&sW[BUF][hl][r][(sc8 ^ SWZ(r)) << 3] = st[idx++];        \
            }                                                                      \
    }

#define MFMA_STEP(BUF)                                                             \
    {                                                                              \
        _Pragma("unroll")                                                          \
        for (int sl = 0; sl < BK / 32; ++sl) {                                     \
            bf16x8 aH[4], aL[4];                                                   \
            _Pragma("unroll")                                                      \
            for (int m = 0; m < 4; ++m) {                                          \
                int r = wr * 64 + m * 16 + (lane & 15);                            \
                int cs = ((sl * 4 + (lane >> 4)) ^ SWZ(r)) << 3;                   \
                aH[m] = *(const bf16x8*)&sA[BUF][0][r][cs];                        \
                aL[m] = *(const bf16x8*)&sA[BUF][1][r][cs];                        \
            }                                                                      \
            _Pragma("unroll")                                                      \
            for (int n = 0; n < 4; ++n) {                                          \
                int rc = wc * 64 + n * 16 + (lane & 15);                           \
                int cs = ((sl * 4 + (lane >> 4)) ^ SWZ(rc)) << 3;                  \
                bf16x8 bH = *(const bf16x8*)&sW[BUF][0][rc][cs];                   \
                bf16x8 bL = *(const bf16x8*)&sW[BUF][1][rc][cs];                   \
                _Pragma("unroll")                                                  \
                for (int m = 0; m < 4; ++m) {                                      \
                    acc[m][n] = __builtin_amdgcn_mfma_f32_16x16x32_bf16(aL[m], bH, acc[m][n], 0, 0, 0); \
                    acc[m][n] = __builtin_amdgcn_mfma_f32_16x16x32_bf16(aH[m], bL, acc[m][n], 0, 0, 0); \
                    acc[m][n] = __builtin_amdgcn_mfma_f32_16x16x32_bf16(aH[m], bH, acc[m][n], 0, 0, 0); \
                }                                                                  \
            }                                                                      \
        }                                                                          \
    }

    f32x4 acc[4][4] = {};

    if (MODE == 3) {
        /* pipelined: one barrier per step; ds_write(t+1) after MFMA(t) */
        LOADK(0);
        WRITELDS(0);
        __syncthreads();
        int cur = 0;
        for (int step = 0; step < NSTEP; ++step) {
            if (step < NSTEP - 1) LOADK((step + 1) * BK);
            if (cur == 0) { MFMA_STEP(0); } else { MFMA_STEP(1); }
            if (step < NSTEP - 1) {
                if (cur == 0) { WRITELDS(1); } else { WRITELDS(0); }
            }
            __syncthreads();
            cur ^= 1;
        }
    } else {
        /* r11-proven 2-barrier single-buffer loop */
        LOADK(0);
        for (int step = 0; step < NSTEP; ++step) {
            __syncthreads();
            WRITELDS(0);
            __syncthreads();
            if (step < NSTEP - 1) LOADK((step + 1) * BK);
            MFMA_STEP(0);
        }
    }

#pragma unroll
    for (int m = 0; m < 4; ++m)
#pragma unroll
        for (int n = 0; n < 4; ++n) {
            size_t col = colBase + wc * 64 + n * 16 + (lane & 15);
            size_t rb  = rowBase + wr * 64 + m * 16 + ((lane >> 4) << 2);
            if (MODE == 3) {
                if (z == 0) {
#pragma unroll
                    for (int r = 0; r < 4; ++r) {
                        ushort oh, ol;
                        split2(acc[m][n][r], oh, ol);
                        Ch[(rb + r) * D_MODEL + col] = oh;
                        Cl[(rb + r) * D_MODEL + col] = ol;
                    }
                } else {
                    float* Cz = C + (size_t)(z - 1) * ROWS_PER_T * D_MODEL;
#pragma unroll
                    for (int r = 0; r < 4; ++r)
                        Cz[(rb + r) * D_MODEL + col] = acc[m][n][r];
                }
            } else {
                float bv = bias[col];
#pragma unroll
                for (int r = 0; r < 4; ++r)
                    C[(rb + r) * D_MODEL + col] = acc[m][n][r] + bv;
            }
        }
#undef LOADK
#undef WRITELDS
#undef MFMA_STEP
#undef SWZ
}

/* ------- Kernel 3: K-side reductions via MFMA (unchanged). ------- */
__global__ __launch_bounds__(256)
void pair_reduce_mfma_kernel(const float* __restrict__ fk, const float* __restrict__ fv,
                             float* __restrict__ partials) {
    int pc = blockIdx.x;
    int pair = pc >> 4, chunk = pc & 15;
    int h = pair & 7, qg = pair >> 3;
    const float* Fk = fk + ((size_t)(qg * NTOK + chunk * 128)) * D_MODEL + h * HDIM;
    const float* Fv = fv + ((size_t)(qg * NTOK + chunk * 128)) * D_MODEL + h * HDIM;
    __shared__ float fkT[64][132];
    __shared__ float fvT[64][132];
    __shared__ float rkn_s[128], kvar_s[128];
    __shared__ float uvp[4][64];
    int tid = threadIdx.x, lane = tid & 63, wid = tid >> 6;
    int tn = tid >> 2;
    int fb = (tid & 3) << 2;
#pragma unroll
    for (int pass = 0; pass < 2; ++pass) {
        int n = pass * 64 + tn;
        float x[16], y[16];
#pragma unroll
        for (int j4 = 0; j4 < 4; ++j4) {
            *(float4*)&x[j4 * 4] = *(const float4*)(Fk + (size_t)n * D_MODEL + fb + j4 * 16);
            *(float4*)&y[j4 * 4] = *(const float4*)(Fv + (size_t)n * D_MODEL + fb + j4 * 16);
        }
        float s = 0.f, sq = 0.f;
#pragma unroll
        for (int j = 0; j < 16; ++j) { s += x[j]; sq += x[j] * x[j]; }
        s  += __shfl_xor(s, 1);  s  += __shfl_xor(s, 2);
        sq += __shfl_xor(sq, 1); sq += __shfl_xor(sq, 2);
        if ((tid & 3) == 0) {
            rkn_s[n]  = 1.0f / sqrtf(sq);
            kvar_s[n] = (sq - s * s * (1.0f / 64.0f)) * (1.0f / 63.0f);
        }
#pragma unroll
        for (int j4 = 0; j4 < 4; ++j4)
#pragma unroll
            for (int i = 0; i < 4; ++i) {
                fkT[fb + j4 * 16 + i][n] = x[j4 * 4 + i];
                fvT[fb + j4 * 16 + i][n] = y[j4 * 4 + i];
            }
    }
    __syncthreads();

    {
        float acc = 0.f;
#pragma unroll
        for (int j4 = 0; j4 < 8; ++j4) {
            float4 kv  = *(const float4*)&kvar_s[wid * 32 + j4 * 4];
            float4 f4  = *(const float4*)&fvT[lane][wid * 32 + j4 * 4];
            acc += kv.x * f4.x + kv.y * f4.y + kv.z * f4.z + kv.w * f4.w;
        }
        uvp[wid][lane] = acc;
    }

    int wm = wid >> 1, wn = wid & 1;
    int fr = lane & 15, kg = (lane >> 4) << 3;
    f32x4 accP[2][2] = {}, accC[2][2] = {};
#pragma unroll
    for (int t = 0; t < 4; ++t) {
        int k0 = t * 32 + kg;
        float4 rk0 = *(const float4*)&rkn_s[k0];
        float4 rk1 = *(const float4*)&rkn_s[k0 + 4];
        bf16x8 aRH[2], aRL[2], aSH[2], aSL[2], bH[2], bL[2];
#pragma unroll
        for (int m = 0; m < 2; ++m) {
            int a = wm * 32 + m * 16 + fr;
            float4 r0 = *(const float4*)&fkT[a][k0];
            float4 r1 = *(const float4*)&fkT[a][k0 + 4];
            split8v(r0, r1, aRH[m], aRL[m]);
            float4 s0 = make_float4(r0.x * rk0.x, r0.y * rk0.y, r0.z * rk0.z, r0.w * rk0.w);
            float4 s1 = make_float4(r1.x * rk1.x, r1.y * rk1.y, r1.z * rk1.z, r1.w * rk1.w);
            split8v(s0, s1, aSH[m], aSL[m]);
        }
#pragma unroll
        for (int n = 0; n < 2; ++n) {
            int c = wn * 32 + n * 16 + fr;
            float4 r0 = *(const float4*)&fvT[c][k0];
            float4 r1 = *(const float4*)&fvT[c][k0 + 4];
            split8v(r0, r1, bH[n], bL[n]);
        }
#pragma unroll
        for (int m = 0; m < 2; ++m)
#pragma unroll
            for (int n = 0; n < 2; ++n) {
                accP[m][n] = __builtin_amdgcn_mfma_f32_16x16x32_bf16(aSL[m], bH[n], accP[m][n], 0, 0, 0);
                accP[m][n] = __builtin_amdgcn_mfma_f32_16x16x32_bf16(aSH[m], bL[n], accP[m][n], 0, 0, 0);
                accP[m][n] = __builtin_amdgcn_mfma_f32_16x16x32_bf16(aSH[m], bH[n], accP[m][n], 0, 0, 0);
                accC[m][n] = __builtin_amdgcn_mfma_f32_16x16x32_bf16(aRL[m], bH[n], accC[m][n], 0, 0, 0);
                accC[m][n] = __builtin_amdgcn_mfma_f32_16x16x32_bf16(aRH[m], bL[n], accC[m][n], 0, 0, 0);
                accC[m][n] = __builtin_amdgcn_mfma_f32_16x16x32_bf16(aRH[m], bH[n], accC[m][n], 0, 0, 0);
            }
    }

    float* outp = partials + (size_t)pc * 8256;
#pragma unroll
    for (int m = 0; m < 2; ++m)
#pragma unroll
        for (int n = 0; n < 2; ++n) {
            int a0 = wm * 32 + m * 16 + ((lane >> 4) << 2);
            int c  = wn * 32 + n * 16 + fr;
#pragma unroll
            for (int r = 0; r < 4; ++r) {
                outp[(a0 + r) * 64 + c]        = accP[m][n][r];
                outp[4096 + (a0 + r) * 64 + c] = accC[m][n][r];
            }
        }
    __syncthreads();
    if (tid < 64)
        outp[8192 + tid] = uvp[0][tid] + uvp[1][tid] + uvp[2][tid] + uvp[3][tid];
}

/* -------- Kernel 4: reduce NCHUNK partials per pair (grid = 32 pairs x 8 slices) -------- */
__global__ __launch_bounds__(256)
void pair_finalize_kernel(const float* __restrict__ partials, float* __restrict__ pairacc) {
    int pair = blockIdx.x >> 3, sl = blockIdx.x & 7;
    int e0 = sl * 1032, e1 = e0 + 1032;
    for (int e = e0 + threadIdx.x; e < e1; e += 256) {
        float s = 0.f;
        for (int c = 0; c < NCHUNK; ++c)
            s += partials[((size_t)(pair * NCHUNK + c)) * 8256 + e];
        pairacc[(size_t)pair * 8320 + e] = s;
    }
}

/* -------- Kernel 5: Q-side apply via MFMA (computes Cv col-sums locally). -------- */
__global__ __launch_bounds__(256)
void q_apply_mfma_kernel(const ushort* __restrict__ Fqh, const ushort* __restrict__ Fql,
                         const float* __restrict__ pairacc,
                         const float* __restrict__ cov_raw, const float* __restrict__ var_raw,
                         ushort* __restrict__ Oh, ushort* __restrict__ Ol) {
    int pair = blockIdx.x >> 4, chunk = blockIdx.x & 15;
    int h = pair & 7, qg = pair >> 3;
    __shared__ float PT[64][68];
    __shared__ float CT[64][68];
    __shared__ float u_s[64], sc_s[64];
    const float* pa = pairacc + (size_t)pair * 8320;
    for (int e = threadIdx.x; e < 4096; e += 256) {
        int a = e >> 6, c = e & 63;
        PT[c][a] = pa[e];
        CT[c][a] = pa[4096 + e];
    }
    if (threadIdx.x < 64) u_s[threadIdx.x] = pa[8192 + threadIdx.x];
    __syncthreads();
    if (threadIdx.x < 64) {
        float s = 0.f;
#pragma unroll
        for (int a = 0; a < 64; ++a) s += CT[threadIdx.x][a];
        sc_s[threadIdx.x] = s;
    }
    __syncthreads();
    int tid = threadIdx.x, lane = tid & 63, wave = tid >> 6;
    size_t row0 = (size_t)qg * NTOK + (size_t)chunk * 128 + wave * 32;
    const ushort* qhp = Fqh + row0 * D_MODEL + h * HDIM;
    const ushort* qlp = Fql + row0 * D_MODEL + h * HDIM;

    bf16x8 aH[2][2], aL[2][2];
    float qsum[2], qsq[2];
#pragma unroll
    for (int m = 0; m < 2; ++m) {
        int r = m * 16 + (lane & 15);
        int k0 = (lane >> 4) * 8;
        float s = 0.f, sq = 0.f;
#pragma unroll
        for (int ks = 0; ks < 2; ++ks) {
            short8 hv = *(const short8*)(qhp + (size_t)r * D_MODEL + ks * 32 + k0);
            short8 lv = *(const short8*)(qlp + (size_t)r * D_MODEL + ks * 32 + k0);
            aH[m][ks] = *(const bf16x8*)&hv;
            aL[m][ks] = *(const bf16x8*)&lv;
#pragma unroll
            for (int j = 0; j < 8; ++j) {
                float val = b2f((ushort)hv[j]) + b2f((ushort)lv[j]);
                s += val; sq += val * val;
            }
        }
        s  += __shfl_xor(s, 16);  s  += __shfl_xor(s, 32);
        sq += __shfl_xor(sq, 16); sq += __shfl_xor(sq, 32);
        qsum[m] = s; qsq[m] = sq;
    }

    f32x4 accP[2][4] = {}, accC[2][4] = {};
#pragma unroll
    for (int n = 0; n < 4; ++n) {
        int c = n * 16 + (lane & 15);
#pragma unroll
        for (int ks = 0; ks < 2; ++ks) {
            int kb = ks * 32 + (lane >> 4) * 8;
            {
                float4 p0 = *(const float4*)&PT[c][kb];
                float4 p1 = *(const float4*)&PT[c][kb + 4];
                bf16x8 bH, bL;
                split8v(p0, p1, bH, bL);
#pragma unroll
                for (int m = 0; m < 2; ++m) {
                    accP[m][n] = __builtin_amdgcn_mfma_f32_16x16x32_bf16(aL[m][ks], bH, accP[m][n], 0, 0, 0);
                    accP[m][n] = __builtin_amdgcn_mfma_f32_16x16x32_bf16(aH[m][ks], bL, accP[m][n], 0, 0, 0);
                    accP[m][n] = __builtin_amdgcn_mfma_f32_16x16x32_bf16(aH[m][ks], bH, accP[m][n], 0, 0, 0);
                }
            }
            {
                float4 p0 = *(const float4*)&CT[c][kb];
                float4 p1 = *(const float4*)&CT[c][kb + 4];
                bf16x8 bH, bL;
                split8v(p0, p1, bH, bL);
#pragma unroll
                for (int m = 0; m < 2; ++m) {
                    accC[m][n] = __builtin_amdgcn_mfma_f32_16x16x32_bf16(aL[m][ks], bH, accC[m][n], 0, 0, 0);
                    accC[m][n] = __builtin_amdgcn_mfma_f32_16x16x32_bf16(aH[m][ks], bL, accC[m][n], 0, 0, 0);
                    accC[m][n] = __builtin_amdgcn_mfma_f32_16x16x32_bf16(aH[m][ks], bH, accC[m][n], 0, 0, 0);
                }
            }
        }
    }

    float cw = 1.0f / (1.0f + expf(-cov_raw[0]));
    float vw = 1.0f / (1.0f + expf(-var_raw[0]));
    float cos_w = 1.0f - cw - vw;
    float cw_cov = cw * (1.0f / 64.0f);
    float cw_var = vw * (1.0f / 64.0f);
#pragma unroll
    for (int n = 0; n < 4; ++n) {
        int c = n * 16 + (lane & 15);
        float u_c  = u_s[c];
        float sc_c = sc_s[c];
#pragma unroll
        for (int m = 0; m < 2; ++m)
#pragma unroll
            for (int i = 0; i < 4; ++i) {
                int rp = ((lane >> 4) << 2) + i;
                float s  = __shfl(qsum[m], rp);
                float sq = __shfl(qsq[m], rp);
                float qmean = s * (1.0f / 64.0f);
                float rqn   = 1.0f / sqrtf(sq);
                float qvar  = (sq - s * qmean) * (1.0f / 63.0f);
                float res = cos_w * rqn * accP[m][n][i]
                          + cw_cov * (accC[m][n][i] - qmean * sc_c)
                          + cw_var * qvar * u_c;
                ushort oh, ol;
                split2(res, oh, ol);
                size_t o = (row0 + m * 16 + rp) * D_MODEL + h * HDIM + c;
                Oh[o] = oh;
                Ol[o] = ol;
            }
    }
}

extern "C" void kernel_launch(void* const* d_in, const int* in_sizes, int n_in,
                              void* d_out, int out_size, void* d_ws, size_t ws_size,
                              hipStream_t stream) {
    const float* q     = (const float*)d_in[0];
    const float* k     = (const float*)d_in[1];
    const float* v     = (const float*)d_in[2];
    const float* gamma = (const float*)d_in[3];
    const float* beta  = (const float*)d_in[4];
    const float* w_in  = (const float*)d_in[5];
    const float* w_out = (const float*)d_in[6];
    const float* b_out = (const float*)d_in[7];
    const float* cov_r = (const float*)d_in[8];
    const float* var_r = (const float*)d_in[9];
    float* out = (float*)d_out;

    /* workspace layout, NO aliasing (~153 MB; d_ws is 268 MB per poison fill). */
    const size_t E = (size_t)ROWS_PER_T * D_MODEL;            /* 4,194,304 */
    float*  ws       = (float*)d_ws;
    float*  fk       = ws;
    float*  fv       = fk + E;
    ushort* Fqh      = (ushort*)(fv + E);
    ushort* Fql      = Fqh + E;
    ushort* A3h      = Fql + E;                               /* [3][8192][512] u16 */
    ushort* A3l      = A3h + 3 * E;
    ushort* Whi      = A3l + 3 * E;                           /* 512*512 u16 each */
    ushort* Wli      = Whi + D_MODEL * D_MODEL;
    ushort* Who      = Wli + D_MODEL * D_MODEL;
    ushort* Wlo      = Who + D_MODEL * D_MODEL;
    ushort* Oh       = Wlo + D_MODEL * D_MODEL;
    ushort* Ol       = Oh + E;
    float*  partials = (float*)(Ol + E);                      /* 512*8256 f32 */
    float*  pairacc  = partials + (size_t)32 * NCHUNK * 8256; /* 32*8320 f32 */

    /* 1: LN+split q/k/v AND weight splits, one launch */
    hipLaunchKernelGGL(prep_kernel, dim3(3 * ROWS_PER_T / 4 + 256), dim3(256), 0, stream,
                       q, k, v, gamma, beta, w_in, w_out,
                       A3h, A3l, Whi, Wli, Who, Wlo);
    /* 2: all three input GEMMs, BK=32, dbuf 1-barrier pipeline, XCD grid */
    hipLaunchKernelGGL((gemm_split_kernel<3, 32>), dim3(768), dim3(256), 0, stream,
                       A3h, A3l, Whi, Wli, (const float*)nullptr, fk, Fqh, Fql);
    /* 3: K-side reductions */
    hipLaunchKernelGGL(pair_reduce_mfma_kernel, dim3(32 * NCHUNK), dim3(256), 0, stream,
                       fk, fv, partials);
    /* 4: finalize pair accumulators */
    hipLaunchKernelGGL(pair_finalize_kernel, dim3(32 * 8), dim3(256), 0, stream,
                       partials, pairacc);
    /* 5: Q-side apply -> attn-out hi/lo */
    hipLaunchKernelGGL(q_apply_mfma_kernel, dim3(512), dim3(256), 0, stream,
                       Fqh, Fql, pairacc, cov_r, var_r, Oh, Ol);
    /* 6: out-projection GEMM + bias, BK=64 single-buffer (r11-proven), XCD grid */
    hipLaunchKernelGGL((gemm_split_kernel<2, 64>), dim3(256), dim3(256), 0, stream,
                       Oh, Ol, Who, Wlo, b_out, out, (ushort*)nullptr, (ushort*)nullptr);
}

// Round 16
// 114.366 us; speedup vs baseline: 1.0839x; 1.0839x over previous
//
#include <hip/hip_runtime.h>
#include <hip/hip_bf16.h>
#include <math.h>

#define D_MODEL 512
#define NTOK 2048
#define QGRP 4
#define NHEAD 8
#define HDIM 64
#define ROWS_PER_T (QGRP * NTOK)          /* 8192 */
#define LN_EPS 1e-5f
#define NCHUNK 16                          /* pair_reduce chunks per pair */

typedef __attribute__((ext_vector_type(8))) short short8;
typedef __attribute__((ext_vector_type(8))) __bf16 bf16x8;
typedef __attribute__((ext_vector_type(4))) float f32x4;

__device__ inline void split2(float y, ushort& h, ushort& l) {
    __hip_bfloat16 hb = __float2bfloat16(y);
    float hf = __bfloat162float(hb);
    __hip_bfloat16 lb = __float2bfloat16(y - hf);
    h = *reinterpret_cast<ushort*>(&hb);
    l = *reinterpret_cast<ushort*>(&lb);
}

__device__ inline float b2f(ushort u) {
    unsigned int x = ((unsigned int)u) << 16;
    return __uint_as_float(x);
}

__device__ inline void split8v(const float4& p0, const float4& p1, bf16x8& bh, bf16x8& bl) {
    float xv[8] = {p0.x, p0.y, p0.z, p0.w, p1.x, p1.y, p1.z, p1.w};
    ushort hs[8], ls[8];
#pragma unroll
    for (int j = 0; j < 8; ++j) split2(xv[j], hs[j], ls[j]);
    bh = *(const bf16x8*)hs;
    bl = *(const bf16x8*)ls;
}

/* ------- Kernel 1: prep — LN+split of q/k/v (blocks 0..6143) AND
   hi/lo split of both weight matrices (blocks 6144..6399) in ONE launch ------- */
__global__ __launch_bounds__(256)
void prep_kernel(const float* __restrict__ q, const float* __restrict__ k,
                 const float* __restrict__ v, const float* __restrict__ gamma,
                 const float* __restrict__ beta,
                 const float* __restrict__ W0, const float* __restrict__ W1,
                 ushort* __restrict__ A3h, ushort* __restrict__ A3l,
                 ushort* __restrict__ Wh0, ushort* __restrict__ Wl0,
                 ushort* __restrict__ Wh1, ushort* __restrict__ Wl1) {
    if (blockIdx.x >= 6144) {                 /* weight split */
        int b = blockIdx.x - 6144;
        int half = b >> 7;
        const float* W = half ? W1 : W0;
        ushort* Wh = half ? Wh1 : Wh0;
        ushort* Wl = half ? Wl1 : Wl0;
        size_t i = ((size_t)(b & 127) * 256 + threadIdx.x) * 8;
        float4 a = *(const float4*)(W + i);
        float4 bb = *(const float4*)(W + i + 4);
        float xv[8] = {a.x, a.y, a.z, a.w, bb.x, bb.y, bb.z, bb.w};
        ushort hs[8], ls[8];
#pragma unroll
        for (int j = 0; j < 8; ++j) split2(xv[j], hs[j], ls[j]);
        *(short8*)(Wh + i) = *(const short8*)hs;
        *(short8*)(Wl + i) = *(const short8*)ls;
        return;
    }
    int wave = threadIdx.x >> 6, lane = threadIdx.x & 63;
    size_t row = (size_t)blockIdx.x * 4 + wave;      /* 0 .. 24575 */
    int t = (int)(row >> 13);
    size_t r = row & 8191;
    const float* src = (t == 0 ? q : (t == 1 ? k : v)) + r * D_MODEL + lane * 8;
    float4 a = *(const float4*)src;
    float4 b = *(const float4*)(src + 4);
    float s  = a.x + a.y + a.z + a.w + b.x + b.y + b.z + b.w;
    float sq = a.x*a.x + a.y*a.y + a.z*a.z + a.w*a.w
             + b.x*b.x + b.y*b.y + b.z*b.z + b.w*b.w;
    for (int m = 1; m < 64; m <<= 1) {
        s  += __shfl_xor(s, m);
        sq += __shfl_xor(sq, m);
    }
    float mu   = s * (1.0f / (float)D_MODEL);
    float var  = sq * (1.0f / (float)D_MODEL) - mu * mu;
    float rstd = 1.0f / sqrtf(var + LN_EPS);
    float4 g0 = *(const float4*)(gamma + lane * 8);
    float4 g1 = *(const float4*)(gamma + lane * 8 + 4);
    float4 t0 = *(const float4*)(beta + lane * 8);
    float4 t1 = *(const float4*)(beta + lane * 8 + 4);
    float xv[8] = {a.x, a.y, a.z, a.w, b.x, b.y, b.z, b.w};
    float gv[8] = {g0.x, g0.y, g0.z, g0.w, g1.x, g1.y, g1.z, g1.w};
    float bv[8] = {t0.x, t0.y, t0.z, t0.w, t1.x, t1.y, t1.z, t1.w};
    ushort hs[8], ls[8];
#pragma unroll
    for (int j = 0; j < 8; ++j) {
        float y = (xv[j] - mu) * rstd * gv[j] + bv[j];
        split2(y, hs[j], ls[j]);
    }
    *(short8*)(A3h + row * D_MODEL + lane * 8) = *(const short8*)hs;
    *(short8*)(A3l + row * D_MODEL + lane * 8) = *(const short8*)ls;
}

/* ------- Kernel 2: split-bf16 MFMA GEMM, 128x128 tile, 4 waves (r11-proven).
   Reg-staged 2-barrier loop; next step's global loads issued before MFMAs.
   Conflict-free XOR swizzle (verified r6/r9):
     BK=32: SWZ(r) = (r>>1)&3   BK=64: SWZ(r) = r&7
   XCD-aware 1-D grid (T1, bijective: nwg%8==0): each XCD gets a contiguous
   chunk of (rowpanel, z, colpanel) space -> A-panel L2 reuse within XCD.
   MODE 3: grid 768: lin=(bid&7)*96+(bid>>3); x=lin/12, z=(lin%12)>>2,
           cb=lin&3. z==0 -> bf16 hi/lo out; z==1/2 -> fp32 C (fk/fv).
   MODE 2: grid 256: lin=(bid&7)*32+(bid>>3); x=lin>>2, cb=lin&3; +bias. ------- */
template <int MODE, int BK>
__global__ __launch_bounds__(256)
void gemm_split_kernel(const ushort* __restrict__ Ah, const ushort* __restrict__ Al,
                       const ushort* __restrict__ Wh, const ushort* __restrict__ Wl,
                       const float* __restrict__ bias, float* __restrict__ C,
                       ushort* __restrict__ Ch, ushort* __restrict__ Cl) {
    constexpr int NSTEP = 512 / BK;
    constexpr int NG    = BK / 8;        /* granules per row            */
    constexpr int RPP   = 256 / NG;      /* rows staged per pass        */
    constexpr int NP    = 128 / RPP;     /* passes per matrix half      */

    __shared__ __align__(16) ushort sA[2][128][BK];
    __shared__ __align__(16) ushort sW[2][128][BK];

    int tid  = threadIdx.x;
    int lane = tid & 63, wid = tid >> 6;
    int wr = wid >> 1, wc = wid & 1;
    int z, xblk, cb;
    if (MODE == 3) {
        int lin = (blockIdx.x & 7) * 96 + (blockIdx.x >> 3);
        xblk = lin / 12;
        int rem = lin % 12;
        z  = rem >> 2;
        cb = rem & 3;
    } else {
        int lin = (blockIdx.x & 7) * 32 + (blockIdx.x >> 3);
        xblk = lin >> 2;
        cb   = lin & 3;
        z    = 0;
    }
    size_t rowBase = (size_t)xblk * 128;
    size_t colBase = (size_t)cb * 128;
    size_t zoff = (size_t)z * ROWS_PER_T * D_MODEL;
    const ushort* gA[2] = {Ah + zoff, Al + zoff};
    const ushort* gW[2] = {Wh, Wl};

    int sr  = tid / NG;                  /* staging row (+p*RPP per pass) */
    int sc8 = tid % NG;                  /* staging 8-elem granule        */

#define SWZ(r) ((BK == 64) ? ((r) & 7) : (((r) >> 1) & 3))

    short8 st[4 * NP];

#define LOADK(KT)                                                                  \
    {                                                                              \
        int idx = 0;                                                               \
        _Pragma("unroll")                                                          \
        for (int hl = 0; hl < 2; ++hl)                                             \
            _Pragma("unroll")                                                      \
            for (int p = 0; p < NP; ++p) {                                         \
                int r = p * RPP + sr;                                              \
                st[idx++] = *(const short8*)(gA[hl] + (rowBase + r) * D_MODEL +    \
                                             (KT) + sc8 * 8);                      \
            }                                                                      \
        _Pragma("unroll")                                                          \
        for (int hl = 0; hl < 2; ++hl)                                             \
            _Pragma("unroll")                                                      \
            for (int p = 0; p < NP; ++p) {                                         \
                int r = p * RPP + sr;                                              \
                st[idx++] = *(const short8*)(gW[hl] + (colBase + r) * D_MODEL +    \
                                             (KT) + sc8 * 8);                      \
            }                                                                      \
    }

    f32x4 acc[4][4] = {};

    LOADK(0);
    for (int step = 0; step < NSTEP; ++step) {
        __syncthreads();
        {   /* write staged regs to LDS, swizzled */
            int idx = 0;
#pragma unroll
            for (int hl = 0; hl < 2; ++hl)
#pragma unroll
                for (int p = 0; p < NP; ++p) {
                    int r = p * RPP + sr;
                    *(short8*)&sA[hl][r][(sc8 ^ SWZ(r)) << 3] = st[idx++];
                }
#pragma unroll
            for (int hl = 0; hl < 2; ++hl)
#pragma unroll
                for (int p = 0; p < NP; ++p) {
                    int r = p * RPP + sr;
                    *(short8*)&sW[hl][r][(sc8 ^ SWZ(r)) << 3] = st[idx++];
                }
        }
        __syncthreads();
        if (step < NSTEP - 1) LOADK((step + 1) * BK);
#pragma unroll
        for (int sl = 0; sl < BK / 32; ++sl) {
            bf16x8 aH[4], aL[4];
#pragma unroll
            for (int m = 0; m < 4; ++m) {
                int r = wr * 64 + m * 16 + (lane & 15);
                int cs = ((sl * 4 + (lane >> 4)) ^ SWZ(r)) << 3;
                aH[m] = *(const bf16x8*)&sA[0][r][cs];
                aL[m] = *(const bf16x8*)&sA[1][r][cs];
            }
#pragma unroll
            for (int n = 0; n < 4; ++n) {
                int rc = wc * 64 + n * 16 + (lane & 15);
                int cs = ((sl * 4 + (lane >> 4)) ^ SWZ(rc)) << 3;
                bf16x8 bH = *(const bf16x8*)&sW[0][rc][cs];
                bf16x8 bL = *(const bf16x8*)&sW[1][rc][cs];
#pragma unroll
                for (int m = 0; m < 4; ++m) {
                    acc[m][n] = __builtin_amdgcn_mfma_f32_16x16x32_bf16(aL[m], bH, acc[m][n], 0, 0, 0);
                    acc[m][n] = __builtin_amdgcn_mfma_f32_16x16x32_bf16(aH[m], bL, acc[m][n], 0, 0, 0);
                    acc[m][n] = __builtin_amdgcn_mfma_f32_16x16x32_bf16(aH[m], bH, acc[m][n], 0, 0, 0);
                }
            }
        }
    }
#pragma unroll
    for (int m = 0; m < 4; ++m)
#pragma unroll
        for (int n = 0; n < 4; ++n) {
            size_t col = colBase + wc * 64 + n * 16 + (lane & 15);
            size_t rb  = rowBase + wr * 64 + m * 16 + ((lane >> 4) << 2);
            if (MODE == 3) {
                if (z == 0) {
#pragma unroll
                    for (int r = 0; r < 4; ++r) {
                        ushort oh, ol;
                        split2(acc[m][n][r], oh, ol);
                        Ch[(rb + r) * D_MODEL + col] = oh;
                        Cl[(rb + r) * D_MODEL + col] = ol;
                    }
                } else {
                    float* Cz = C + (size_t)(z - 1) * ROWS_PER_T * D_MODEL;
#pragma unroll
                    for (int r = 0; r < 4; ++r)
                        Cz[(rb + r) * D_MODEL + col] = acc[m][n][r];
                }
            } else {
                float bv = bias[col];
#pragma unroll
                for (int r = 0; r < 4; ++r)
                    C[(rb + r) * D_MODEL + col] = acc[m][n][r] + bv;
            }
        }
#undef LOADK
#undef SWZ
}

/* ------- Kernel 3: K-side reductions via MFMA (unchanged). ------- */
__global__ __launch_bounds__(256)
void pair_reduce_mfma_kernel(const float* __restrict__ fk, const float* __restrict__ fv,
                             float* __restrict__ partials) {
    int pc = blockIdx.x;
    int pair = pc >> 4, chunk = pc & 15;
    int h = pair & 7, qg = pair >> 3;
    const float* Fk = fk + ((size_t)(qg * NTOK + chunk * 128)) * D_MODEL + h * HDIM;
    const float* Fv = fv + ((size_t)(qg * NTOK + chunk * 128)) * D_MODEL + h * HDIM;
    __shared__ float fkT[64][132];
    __shared__ float fvT[64][132];
    __shared__ float rkn_s[128], kvar_s[128];
    __shared__ float uvp[4][64];
    int tid = threadIdx.x, lane = tid & 63, wid = tid >> 6;
    int tn = tid >> 2;
    int fb = (tid & 3) << 2;
#pragma unroll
    for (int pass = 0; pass < 2; ++pass) {
        int n = pass * 64 + tn;
        float x[16], y[16];
#pragma unroll
        for (int j4 = 0; j4 < 4; ++j4) {
            *(float4*)&x[j4 * 4] = *(const float4*)(Fk + (size_t)n * D_MODEL + fb + j4 * 16);
            *(float4*)&y[j4 * 4] = *(const float4*)(Fv + (size_t)n * D_MODEL + fb + j4 * 16);
        }
        float s = 0.f, sq = 0.f;
#pragma unroll
        for (int j = 0; j < 16; ++j) { s += x[j]; sq += x[j] * x[j]; }
        s  += __shfl_xor(s, 1);  s  += __shfl_xor(s, 2);
        sq += __shfl_xor(sq, 1); sq += __shfl_xor(sq, 2);
        if ((tid & 3) == 0) {
            rkn_s[n]  = 1.0f / sqrtf(sq);
            kvar_s[n] = (sq - s * s * (1.0f / 64.0f)) * (1.0f / 63.0f);
        }
#pragma unroll
        for (int j4 = 0; j4 < 4; ++j4)
#pragma unroll
            for (int i = 0; i < 4; ++i) {
                fkT[fb + j4 * 16 + i][n] = x[j4 * 4 + i];
                fvT[fb + j4 * 16 + i][n] = y[j4 * 4 + i];
            }
    }
    __syncthreads();

    {
        float acc = 0.f;
#pragma unroll
        for (int j4 = 0; j4 < 8; ++j4) {
            float4 kv  = *(const float4*)&kvar_s[wid * 32 + j4 * 4];
            float4 f4  = *(const float4*)&fvT[lane][wid * 32 + j4 * 4];
            acc += kv.x * f4.x + kv.y * f4.y + kv.z * f4.z + kv.w * f4.w;
        }
        uvp[wid][lane] = acc;
    }

    int wm = wid >> 1, wn = wid & 1;
    int fr = lane & 15, kg = (lane >> 4) << 3;
    f32x4 accP[2][2] = {}, accC[2][2] = {};
#pragma unroll
    for (int t = 0; t < 4; ++t) {
        int k0 = t * 32 + kg;
        float4 rk0 = *(const float4*)&rkn_s[k0];
        float4 rk1 = *(const float4*)&rkn_s[k0 + 4];
        bf16x8 aRH[2], aRL[2], aSH[2], aSL[2], bH[2], bL[2];
#pragma unroll
        for (int m = 0; m < 2; ++m) {
            int a = wm * 32 + m * 16 + fr;
            float4 r0 = *(const float4*)&fkT[a][k0];
            float4 r1 = *(const float4*)&fkT[a][k0 + 4];
            split8v(r0, r1, aRH[m], aRL[m]);
            float4 s0 = make_float4(r0.x * rk0.x, r0.y * rk0.y, r0.z * rk0.z, r0.w * rk0.w);
            float4 s1 = make_float4(r1.x * rk1.x, r1.y * rk1.y, r1.z * rk1.z, r1.w * rk1.w);
            split8v(s0, s1, aSH[m], aSL[m]);
        }
#pragma unroll
        for (int n = 0; n < 2; ++n) {
            int c = wn * 32 + n * 16 + fr;
            float4 r0 = *(const float4*)&fvT[c][k0];
            float4 r1 = *(const float4*)&fvT[c][k0 + 4];
            split8v(r0, r1, bH[n], bL[n]);
        }
#pragma unroll
        for (int m = 0; m < 2; ++m)
#pragma unroll
            for (int n = 0; n < 2; ++n) {
                accP[m][n] = __builtin_amdgcn_mfma_f32_16x16x32_bf16(aSL[m], bH[n], accP[m][n], 0, 0, 0);
                accP[m][n] = __builtin_amdgcn_mfma_f32_16x16x32_bf16(aSH[m], bL[n], accP[m][n], 0, 0, 0);
                accP[m][n] = __builtin_amdgcn_mfma_f32_16x16x32_bf16(aSH[m], bH[n], accP[m][n], 0, 0, 0);
                accC[m][n] = __builtin_amdgcn_mfma_f32_16x16x32_bf16(aRL[m], bH[n], accC[m][n], 0, 0, 0);
                accC[m][n] = __builtin_amdgcn_mfma_f32_16x16x32_bf16(aRH[m], bL[n], accC[m][n], 0, 0, 0);
                accC[m][n] = __builtin_amdgcn_mfma_f32_16x16x32_bf16(aRH[m], bH[n], accC[m][n], 0, 0, 0);
            }
    }

    float* outp = partials + (size_t)pc * 8256;
#pragma unroll
    for (int m = 0; m < 2; ++m)
#pragma unroll
        for (int n = 0; n < 2; ++n) {
            int a0 = wm * 32 + m * 16 + ((lane >> 4) << 2);
            int c  = wn * 32 + n * 16 + fr;
#pragma unroll
            for (int r = 0; r < 4; ++r) {
                outp[(a0 + r) * 64 + c]        = accP[m][n][r];
                outp[4096 + (a0 + r) * 64 + c] = accC[m][n][r];
            }
        }
    __syncthreads();
    if (tid < 64)
        outp[8192 + tid] = uvp[0][tid] + uvp[1][tid] + uvp[2][tid] + uvp[3][tid];
}

/* -------- Kernel 4: reduce NCHUNK partials per pair (grid = 32 pairs x 8 slices) -------- */
__global__ __launch_bounds__(256)
void pair_finalize_kernel(const float* __restrict__ partials, float* __restrict__ pairacc) {
    int pair = blockIdx.x >> 3, sl = blockIdx.x & 7;
    int e0 = sl * 1032, e1 = e0 + 1032;
    for (int e = e0 + threadIdx.x; e < e1; e += 256) {
        float s = 0.f;
        for (int c = 0; c < NCHUNK; ++c)
            s += partials[((size_t)(pair * NCHUNK + c)) * 8256 + e];
        pairacc[(size_t)pair * 8320 + e] = s;
    }
}

/* -------- Kernel 5: Q-side apply via MFMA (computes Cv col-sums locally). -------- */
__global__ __launch_bounds__(256)
void q_apply_mfma_kernel(const ushort* __restrict__ Fqh, const ushort* __restrict__ Fql,
                         const float* __restrict__ pairacc,
                         const float* __restrict__ cov_raw, const float* __restrict__ var_raw,
                         ushort* __restrict__ Oh, ushort* __restrict__ Ol) {
    int pair = blockIdx.x >> 4, chunk = blockIdx.x & 15;
    int h = pair & 7, qg = pair >> 3;
    __shared__ float PT[64][68];
    __shared__ float CT[64][68];
    __shared__ float u_s[64], sc_s[64];
    const float* pa = pairacc + (size_t)pair * 8320;
    for (int e = threadIdx.x; e < 4096; e += 256) {
        int a = e >> 6, c = e & 63;
        PT[c][a] = pa[e];
        CT[c][a] = pa[4096 + e];
    }
    if (threadIdx.x < 64) u_s[threadIdx.x] = pa[8192 + threadIdx.x];
    __syncthreads();
    if (threadIdx.x < 64) {
        float s = 0.f;
#pragma unroll
        for (int a = 0; a < 64; ++a) s += CT[threadIdx.x][a];
        sc_s[threadIdx.x] = s;
    }
    __syncthreads();
    int tid = threadIdx.x, lane = tid & 63, wave = tid >> 6;
    size_t row0 = (size_t)qg * NTOK + (size_t)chunk * 128 + wave * 32;
    const ushort* qhp = Fqh + row0 * D_MODEL + h * HDIM;
    const ushort* qlp = Fql + row0 * D_MODEL + h * HDIM;

    bf16x8 aH[2][2], aL[2][2];
    float qsum[2], qsq[2];
#pragma unroll
    for (int m = 0; m < 2; ++m) {
        int r = m * 16 + (lane & 15);
        int k0 = (lane >> 4) * 8;
        float s = 0.f, sq = 0.f;
#pragma unroll
        for (int ks = 0; ks < 2; ++ks) {
            short8 hv = *(const short8*)(qhp + (size_t)r * D_MODEL + ks * 32 + k0);
            short8 lv = *(const short8*)(qlp + (size_t)r * D_MODEL + ks * 32 + k0);
            aH[m][ks] = *(const bf16x8*)&hv;
            aL[m][ks] = *(const bf16x8*)&lv;
#pragma unroll
            for (int j = 0; j < 8; ++j) {
                float val = b2f((ushort)hv[j]) + b2f((ushort)lv[j]);
                s += val; sq += val * val;
            }
        }
        s  += __shfl_xor(s, 16);  s  += __shfl_xor(s, 32);
        sq += __shfl_xor(sq, 16); sq += __shfl_xor(sq, 32);
        qsum[m] = s; qsq[m] = sq;
    }

    f32x4 accP[2][4] = {}, accC[2][4] = {};
#pragma unroll
    for (int n = 0; n < 4; ++n) {
        int c = n * 16 + (lane & 15);
#pragma unroll
        for (int ks = 0; ks < 2; ++ks) {
            int kb = ks * 32 + (lane >> 4) * 8;
            {
                float4 p0 = *(const float4*)&PT[c][kb];
                float4 p1 = *(const float4*)&PT[c][kb + 4];
                bf16x8 bH, bL;
                split8v(p0, p1, bH, bL);
#pragma unroll
                for (int m = 0; m < 2; ++m) {
                    accP[m][n] = __builtin_amdgcn_mfma_f32_16x16x32_bf16(aL[m][ks], bH, accP[m][n], 0, 0, 0);
                    accP[m][n] = __builtin_amdgcn_mfma_f32_16x16x32_bf16(aH[m][ks], bL, accP[m][n], 0, 0, 0);
                    accP[m][n] = __builtin_amdgcn_mfma_f32_16x16x32_bf16(aH[m][ks], bH, accP[m][n], 0, 0, 0);
                }
            }
            {
                float4 p0 = *(const float4*)&CT[c][kb];
                float4 p1 = *(const float4*)&CT[c][kb + 4];
                bf16x8 bH, bL;
                split8v(p0, p1, bH, bL);
#pragma unroll
                for (int m = 0; m < 2; ++m) {
                    accC[m][n] = __builtin_amdgcn_mfma_f32_16x16x32_bf16(aL[m][ks], bH, accC[m][n], 0, 0, 0);
                    accC[m][n] = __builtin_amdgcn_mfma_f32_16x16x32_bf16(aH[m][ks], bL, accC[m][n], 0, 0, 0);
                    accC[m][n] = __builtin_amdgcn_mfma_f32_16x16x32_bf16(aH[m][ks], bH, accC[m][n], 0, 0, 0);
                }
            }
        }
    }

    float cw = 1.0f / (1.0f + expf(-cov_raw[0]));
    float vw = 1.0f / (1.0f + expf(-var_raw[0]));
    float cos_w = 1.0f - cw - vw;
    float cw_cov = cw * (1.0f / 64.0f);
    float cw_var = vw * (1.0f / 64.0f);
#pragma unroll
    for (int n = 0; n < 4; ++n) {
        int c = n * 16 + (lane & 15);
        float u_c  = u_s[c];
        float sc_c = sc_s[c];
#pragma unroll
        for (int m = 0; m < 2; ++m)
#pragma unroll
            for (int i = 0; i < 4; ++i) {
                int rp = ((lane >> 4) << 2) + i;
                float s  = __shfl(qsum[m], rp);
                float sq = __shfl(qsq[m], rp);
                float qmean = s * (1.0f / 64.0f);
                float rqn   = 1.0f / sqrtf(sq);
                float qvar  = (sq - s * qmean) * (1.0f / 63.0f);
                float res = cos_w * rqn * accP[m][n][i]
                          + cw_cov * (accC[m][n][i] - qmean * sc_c)
                          + cw_var * qvar * u_c;
                ushort oh, ol;
                split2(res, oh, ol);
                size_t o = (row0 + m * 16 + rp) * D_MODEL + h * HDIM + c;
                Oh[o] = oh;
                Ol[o] = ol;
            }
    }
}

extern "C" void kernel_launch(void* const* d_in, const int* in_sizes, int n_in,
                              void* d_out, int out_size, void* d_ws, size_t ws_size,
                              hipStream_t stream) {
    const float* q     = (const float*)d_in[0];
    const float* k     = (const float*)d_in[1];
    const float* v     = (const float*)d_in[2];
    const float* gamma = (const float*)d_in[3];
    const float* beta  = (const float*)d_in[4];
    const float* w_in  = (const float*)d_in[5];
    const float* w_out = (const float*)d_in[6];
    const float* b_out = (const float*)d_in[7];
    const float* cov_r = (const float*)d_in[8];
    const float* var_r = (const float*)d_in[9];
    float* out = (float*)d_out;

    /* workspace layout, NO aliasing (~153 MB; d_ws is 268 MB per poison fill). */
    const size_t E = (size_t)ROWS_PER_T * D_MODEL;            /* 4,194,304 */
    float*  ws       = (float*)d_ws;
    float*  fk       = ws;
    float*  fv       = fk + E;
    ushort* Fqh      = (ushort*)(fv + E);
    ushort* Fql      = Fqh + E;
    ushort* A3h      = Fql + E;                               /* [3][8192][512] u16 */
    ushort* A3l      = A3h + 3 * E;
    ushort* Whi      = A3l + 3 * E;                           /* 512*512 u16 each */
    ushort* Wli      = Whi + D_MODEL * D_MODEL;
    ushort* Who      = Wli + D_MODEL * D_MODEL;
    ushort* Wlo      = Who + D_MODEL * D_MODEL;
    ushort* Oh       = Wlo + D_MODEL * D_MODEL;
    ushort* Ol       = Oh + E;
    float*  partials = (float*)(Ol + E);                      /* 512*8256 f32 */
    float*  pairacc  = partials + (size_t)32 * NCHUNK * 8256; /* 32*8320 f32 */

    /* 1: LN+split q/k/v AND weight splits, one launch */
    hipLaunchKernelGGL(prep_kernel, dim3(3 * ROWS_PER_T / 4 + 256), dim3(256), 0, stream,
                       q, k, v, gamma, beta, w_in, w_out,
                       A3h, A3l, Whi, Wli, Who, Wlo);
    /* 2: all three input GEMMs, BK=32, XCD-chunked 1-D grid (768) */
    hipLaunchKernelGGL((gemm_split_kernel<3, 32>), dim3(768), dim3(256), 0, stream,
                       A3h, A3l, Whi, Wli, (const float*)nullptr, fk, Fqh, Fql);
    /* 3: K-side reductions */
    hipLaunchKernelGGL(pair_reduce_mfma_kernel, dim3(32 * NCHUNK), dim3(256), 0, stream,
                       fk, fv, partials);
    /* 4: finalize pair accumulators */
    hipLaunchKernelGGL(pair_finalize_kernel, dim3(32 * 8), dim3(256), 0, stream,
                       partials, pairacc);
    /* 5: Q-side apply -> attn-out hi/lo */
    hipLaunchKernelGGL(q_apply_mfma_kernel, dim3(512), dim3(256), 0, stream,
                       Fqh, Fql, pairacc, cov_r, var_r, Oh, Ol);
    /* 6: out-projection GEMM + bias, BK=64, XCD-chunked 1-D grid (256) */
    hipLaunchKernelGGL((gemm_split_kernel<2, 64>), dim3(256), dim3(256), 0, stream,
                       Oh, Ol, Who, Wlo, b_out, out, (ushort*)nullptr, (ushort*)nullptr);
}